// Round 4
// baseline (688.306 us; speedup 1.0000x reference)
//
#include <hip/hip_runtime.h>
#include <math.h>

#define B_  512
#define I_  8
#define C_  1152
#define J_  10
#define S_  16
#define K1  9216
#define NKB 288     // sgemm K-blocks (K=9216/32)
#define KBT 16      // tgemm K-blocks (K=512/32)
#define NB  256     // persistent grid blocks
#define NT  512     // threads per block (8 waves)

typedef short short8 __attribute__((ext_vector_type(8)));
typedef float floatx4 __attribute__((ext_vector_type(4)));

__device__ inline unsigned short f2bf(float f) {
    unsigned int u = __float_as_uint(f);
    return (unsigned short)((u + 0x7FFFu + ((u >> 16) & 1u)) >> 16);
}
__device__ inline unsigned int pack2(float a, float b) {
    return (unsigned int)f2bf(a) | ((unsigned int)f2bf(b) << 16);
}

// Device-scope grid barrier. bar[0]=arrive count, bar[1]=generation.
// Each block's thread0: fence (wbl2 sc1) -> arrive -> spin acquire -> fence (inv).
// Timeout failsafe breaks the spin (fails validation instead of hanging).
__device__ __forceinline__ void grid_bar(int* bar) {
    __syncthreads();
    if (threadIdx.x == 0) {
        __threadfence();
        int g = __hip_atomic_load(&bar[1], __ATOMIC_RELAXED, __HIP_MEMORY_SCOPE_AGENT);
        int old = __hip_atomic_fetch_add(&bar[0], 1, __ATOMIC_ACQ_REL, __HIP_MEMORY_SCOPE_AGENT);
        if (old == NB - 1) {
            __hip_atomic_store(&bar[0], 0, __ATOMIC_RELAXED, __HIP_MEMORY_SCOPE_AGENT);
            __hip_atomic_store(&bar[1], g + 1, __ATOMIC_RELEASE, __HIP_MEMORY_SCOPE_AGENT);
        } else {
            int spins = 0;
            while (__hip_atomic_load(&bar[1], __ATOMIC_ACQUIRE, __HIP_MEMORY_SCOPE_AGENT) == g) {
                __builtin_amdgcn_s_sleep(2);
                if (++spins > (1 << 20)) break;   // ~0.25s failsafe
            }
        }
        __threadfence();
    }
    __syncthreads();
}

__global__ __launch_bounds__(256) void k_init(float* __restrict__ b_ij,
                                              int* __restrict__ bar) {
    int t = blockIdx.x * 256 + threadIdx.x;
    if (t < C_ * J_) b_ij[t] = 0.0f;
    if (t < 16) bar[t] = 0;
}

__global__ __launch_bounds__(NT) void k_persist(
    const float* __restrict__ x, const float* __restrict__ W,
    float* __restrict__ out,
    uint4* __restrict__ Bs4, uint4* __restrict__ Bt4,
    uint4* __restrict__ Wf4, uint4* __restrict__ Af4,
    unsigned short* __restrict__ W2, unsigned short* __restrict__ Vf,
    float* __restrict__ b_ij, int* __restrict__ bar)
{
    const int bid = blockIdx.x;
    const int t   = threadIdx.x;
    const int w   = t >> 6;     // wave 0..7
    const int L   = t & 63;     // lane
    __shared__ float lds[10240];   // 40 KB

    // ================= PACK (2448 tasks) =================
    for (int task = bid; task < 2448; task += NB) {
        __syncthreads();
        if (task < 1152) {                       // --- Bs: x -> sgemm B-frags
            const int nt = task / 36, kbg = task % 36;
            const int b0 = nt * 16, k0 = kbg * 256;
            #pragma unroll
            for (int p = 0; p < 2; p++) {
                int f4 = p * 512 + t;            // 1024 float4 = 16 rows x 64
                int row = f4 >> 6, c4 = (f4 & 63) << 2;
                *(float4*)&lds[row * 260 + c4] =
                    *(const float4*)&x[(size_t)(b0 + row) * K1 + k0 + c4];
            }
            __syncthreads();
            const int q = t >> 6;                // 0..7
            const int row = L & 15;
            const int col = q * 32 + ((L >> 4) << 3);
            const float* s = &lds[row * 260 + col];
            uint4 o;
            o.x = pack2(s[0], s[1]); o.y = pack2(s[2], s[3]);
            o.z = pack2(s[4], s[5]); o.w = pack2(s[6], s[7]);
            Bs4[((size_t)nt * NKB + kbg * 8 + q) * 64 + L] = o;
        } else if (task < 2304) {                // --- Bt: x^T -> tgemm B-frags
            const int b2 = task - 1152;
            const int kb = b2 & 15, ntg = b2 >> 4;
            const int b0 = kb * 32, n0 = ntg * 128;
            #pragma unroll
            for (int p = 0; p < 2; p++) {
                int f4 = p * 512 + t;            // 1024 float4 = 32 rows x 32
                int row = f4 >> 5, c4 = (f4 & 31) << 2;
                *(float4*)&lds[row * 132 + c4] =
                    *(const float4*)&x[(size_t)(b0 + row) * K1 + n0 + c4];
            }
            __syncthreads();
            const int ntl = t >> 6;
            const int bb = (L >> 4) << 3;
            const int nl = ntl * 16 + (L & 15);
            float v[8];
            #pragma unroll
            for (int e = 0; e < 8; e++) v[e] = lds[(bb + e) * 132 + nl];
            uint4 o;
            o.x = pack2(v[0], v[1]); o.y = pack2(v[2], v[3]);
            o.z = pack2(v[4], v[5]); o.w = pack2(v[6], v[7]);
            Bt4[((size_t)(ntg * 8 + ntl) * KBT + kb) * 64 + L] = o;
        } else {                                 // --- W chunk (8 c-rows) -> Wf + W2
            const int c0 = (task - 2304) * 8;
            #pragma unroll
            for (int p = 0; p < 5; p++) {
                int f4 = p * 512 + t;            // 2560 float4 = 8 x 320
                int cc = f4 / 320, off4 = (f4 % 320) << 2;
                *(float4*)&lds[cc * 1280 + off4] =
                    *(const float4*)&W[(size_t)(c0 + cc) * 1280 + off4];
            }
            __syncthreads();
            #pragma unroll
            for (int p = 0; p < 3; p++) {        // Wf: 1280 frags (j,i,m)
                int o = p * 512 + t;
                if (o < 1280) {
                    int j = o >> 7, i = (o >> 4) & 7, m = o & 15;
                    int k0 = i * C_ + c0;
                    int Lw = m | (((k0 >> 3) & 3) << 4);
                    float v[8];
                    #pragma unroll
                    for (int e = 0; e < 8; e++)
                        v[e] = lds[e * 1280 + j * 128 + m * 8 + i];
                    uint4 og;
                    og.x = pack2(v[0], v[1]); og.y = pack2(v[2], v[3]);
                    og.z = pack2(v[4], v[5]); og.w = pack2(v[6], v[7]);
                    Wf4[((size_t)j * NKB + (k0 >> 5)) * 64 + Lw] = og;
                }
            }
            #pragma unroll
            for (int p = 0; p < 2; p++) {        // W2[j][i][c][s] rows
                int o = p * 512 + t;
                if (o < 640) {
                    int j = o >> 6, i = (o >> 3) & 7, cc = o & 7;
                    unsigned int r8[8];
                    #pragma unroll
                    for (int h = 0; h < 8; h++)
                        r8[h] = pack2(lds[cc * 1280 + j * 128 + (2 * h) * 8 + i],
                                      lds[cc * 1280 + j * 128 + (2 * h + 1) * 8 + i]);
                    unsigned short* dst = W2 + ((size_t)(j * 8 + i) * C_ + c0 + cc) * 16;
                    *(uint4*)dst       = make_uint4(r8[0], r8[1], r8[2], r8[3]);
                    *(uint4*)(dst + 8) = make_uint4(r8[4], r8[5], r8[6], r8[7]);
                }
            }
        }
    }
    grid_bar(bar);

    const short8* AfS = (const short8*)Af4;
    const short8* BsS = (const short8*)Bs4;
    const short8* BtS = (const short8*)Bt4;
    const short8* VfS = (const short8*)Vf;

    for (int it = 0; it < 3; it++) {
        // ============ FOLD: Af = softmax(b_ij) * Wf (360 tasks) ============
        for (int task = bid; task < 360; task += NB) {
            __syncthreads();
            const int j   = task / 36;
            const int kb0 = (task % 36) * 8;
            const int k0  = kb0 * 32;            // multiple of 256
            if (t < 256) {
                int c = (k0 + t) % C_;
                float bv[J_], mx = -1e30f;
                #pragma unroll
                for (int jj = 0; jj < J_; jj++) {
                    bv[jj] = b_ij[c * J_ + jj]; mx = fmaxf(mx, bv[jj]);
                }
                float sum = 0.0f;
                #pragma unroll
                for (int jj = 0; jj < J_; jj++) sum += __expf(bv[jj] - mx);
                lds[t] = __expf(bv[j] - mx) / sum;
            }
            __syncthreads();
            const size_t flat = ((size_t)j * NKB + kb0 + w) * 64 + L;
            const int off = w * 32 + ((L >> 4) << 3);
            uint4 wv = Wf4[flat];
            unsigned int u[4] = {wv.x, wv.y, wv.z, wv.w};
            uint4 o; unsigned int* po = (unsigned int*)&o;
            #pragma unroll
            for (int h = 0; h < 4; h++) {
                float f0 = __uint_as_float(u[h] << 16)        * lds[off + 2 * h];
                float f1 = __uint_as_float(u[h] & 0xffff0000u) * lds[off + 2 * h + 1];
                po[h] = pack2(f0, f1);
            }
            Af4[flat] = o;
        }
        grid_bar(bar);

        // ======= SGEMM + REDUCE + SQUASH (80 tasks: 2j x 2nt, K in-block) =======
        for (int task = bid; task < 80; task += NB) {
            __syncthreads();
            const int ntp = task & 15, jp = task >> 4;
            const int j0 = jp * 2, nt0 = ntp * 2;
            const int kb0 = w * 36;
            const short8* pA0 = AfS + ((size_t)j0 * NKB + kb0) * 64 + L;
            const short8* pA1 = pA0 + (size_t)NKB * 64;
            const short8* pB0 = BsS + ((size_t)nt0 * NKB + kb0) * 64 + L;
            const short8* pB1 = pB0 + (size_t)NKB * 64;
            floatx4 c00 = {0.f,0.f,0.f,0.f}, c01 = c00, c10 = c00, c11 = c00;
            #pragma unroll 4
            for (int i = 0; i < 36; i++) {
                short8 a0 = pA0[i * 64], a1 = pA1[i * 64];
                short8 b0 = pB0[i * 64], b1 = pB1[i * 64];
                c00 = __builtin_amdgcn_mfma_f32_16x16x32_bf16(a0, b0, c00, 0, 0, 0);
                c01 = __builtin_amdgcn_mfma_f32_16x16x32_bf16(a0, b1, c01, 0, 0, 0);
                c10 = __builtin_amdgcn_mfma_f32_16x16x32_bf16(a1, b0, c10, 0, 0, 0);
                c11 = __builtin_amdgcn_mfma_f32_16x16x32_bf16(a1, b1, c11, 0, 0, 0);
            }
            const int col = L & 15, rw = (L >> 4) << 2;
            float* base = &lds[w * 1024];
            #pragma unroll
            for (int r = 0; r < 4; r++) {
                base[      (rw + r) * 16 + col] = c00[r];
                base[256 + (rw + r) * 16 + col] = c01[r];
                base[512 + (rw + r) * 16 + col] = c10[r];
                base[768 + (rw + r) * 16 + col] = c11[r];
            }
            __syncthreads();
            if (t < 64) {
                const int jq = t >> 5, nq = (t >> 4) & 1, bl = t & 15;
                const int qoff = (jq * 2 + nq) * 256;
                float sv[16]; float msq = 0.f;
                #pragma unroll
                for (int s = 0; s < 16; s++) {
                    float a = 0.f;
                    #pragma unroll
                    for (int w8 = 0; w8 < 8; w8++)
                        a += lds[w8 * 1024 + qoff + s * 16 + bl];
                    sv[s] = a; msq += a * a;
                }
                const float scale = msq / ((1.f + msq) * sqrtf(msq));
                const int j = j0 + jq;
                const int b = (nt0 + nq) * 16 + bl;
                if (it < 2) {
                    const int kb = b >> 5, lh = (b >> 3) & 3, e = b & 7;
                    #pragma unroll
                    for (int s = 0; s < 16; s++)
                        Vf[((size_t)(j * KBT + kb) * 64 + (s | (lh << 4))) * 8 + e] =
                            f2bf(sv[s] * scale);
                } else {
                    float o16[16];
                    #pragma unroll
                    for (int s = 0; s < 16; s++) o16[s] = sv[s] * scale;
                    float* dst = &out[((size_t)b * J_ + j) * S_];
                    #pragma unroll
                    for (int r4 = 0; r4 < 4; r4++)
                        *(float4*)(dst + r4 * 4) = *(float4*)(o16 + r4 * 4);
                }
            }
        }
        if (it == 2) return;
        grid_bar(bar);

        // ============ TGEMM + fused b_ij update (720 tasks) ============
        for (int task = bid; task < 720; task += NB) {
            __syncthreads();
            const int j = task / 72, ntg = task % 72;
            const int nt = ntg * 8 + w;
            const short8* pA = VfS + (size_t)j * KBT * 64 + L;
            const short8* pB = BtS + (size_t)nt * KBT * 64 + L;
            floatx4 a = {0.f, 0.f, 0.f, 0.f};
            #pragma unroll
            for (int kb = 0; kb < KBT; kb++)
                a = __builtin_amdgcn_mfma_f32_16x16x32_bf16(pA[kb * 64], pB[kb * 64], a, 0, 0, 0);
            const int col = L & 15, rw = (L >> 4) << 2;
            #pragma unroll
            for (int r = 0; r < 4; r++)
                lds[(rw + r) * 132 + w * 16 + col] = a[r];
            __syncthreads();
            if (t < 128) {
                const int n0 = ntg * 128;
                const int i = n0 / C_, c0 = n0 % C_;
                const int c = c0 + t;
                const unsigned short* wp = W2 + ((size_t)(j * 8 + i) * C_ + c) * 16;
                uint4 w0 = *(const uint4*)wp;
                uint4 w1 = *(const uint4*)(wp + 8);
                unsigned int uw[8] = {w0.x, w0.y, w0.z, w0.w, w1.x, w1.y, w1.z, w1.w};
                float sum = 0.f;
                #pragma unroll
                for (int h = 0; h < 8; h++) {
                    sum += lds[(2 * h) * 132 + t]     * __uint_as_float(uw[h] << 16);
                    sum += lds[(2 * h + 1) * 132 + t] * __uint_as_float(uw[h] & 0xffff0000u);
                }
                atomicAdd(&b_ij[c * J_ + j], sum * (1.0f / 512.f));
            }
        }
        grid_bar(bar);
    }
}

// ---------------------------------------------------------------------------
extern "C" void kernel_launch(void* const* d_in, const int* in_sizes, int n_in,
                              void* d_out, int out_size, void* d_ws, size_t ws_size,
                              hipStream_t stream) {
    const float* x = (const float*)d_in[0];   // [512][8][1152]
    const float* W = (const float*)d_in[1];   // [1152][10][16][8]
    float* out = (float*)d_out;               // [512][10][16][1]
    float* ws  = (float*)d_ws;

    // workspace layout (floats, 16B-aligned)
    float* Bs_f = ws;                    // 2,359,296
    float* Bt_f = Bs_f + 2359296;        // 2,359,296
    float* Wf_f = Bt_f + 2359296;        //   737,280
    float* Af_f = Wf_f + 737280;         //   737,280
    float* W2_f = Af_f + 737280;         //   737,280
    float* Vf_f = W2_f + 737280;         //    40,960
    float* bij  = Vf_f + 40960;          //    11,520
    int*   bar  = (int*)(bij + 11520);   //        16
    // total ~6.98M floats = 27.9 MB

    k_init<<<46, 256, 0, stream>>>(bij, bar);
    k_persist<<<NB, NT, 0, stream>>>(x, W, out,
                                     (uint4*)Bs_f, (uint4*)Bt_f,
                                     (uint4*)Wf_f, (uint4*)Af_f,
                                     (unsigned short*)W2_f, (unsigned short*)Vf_f,
                                     bij, bar);
}

// Round 5
// 352.981 us; speedup vs baseline: 1.9500x; 1.9500x over previous
//
#include <hip/hip_runtime.h>
#include <math.h>

#define B_  512
#define I_  8
#define C_  1152
#define J_  10
#define S_  16
#define K1  9216
#define NKB 288     // sgemm K-blocks (K=9216/32)
#define KBT 16      // tgemm K-blocks (K=512/32)
#define NB  256     // persistent grid blocks
#define NT  512     // threads per block (8 waves)

typedef short short8 __attribute__((ext_vector_type(8)));
typedef float floatx4 __attribute__((ext_vector_type(4)));

__device__ inline unsigned short f2bf(float f) {
    unsigned int u = __float_as_uint(f);
    return (unsigned short)((u + 0x7FFFu + ((u >> 16) & 1u)) >> 16);
}
__device__ inline unsigned int pack2(float a, float b) {
    return (unsigned int)f2bf(a) | ((unsigned int)f2bf(b) << 16);
}

// Device-scope grid barrier, cache-benign version.
// - arrive: RELEASE fetch_add (one wbl2/block — flushes this block's writes)
// - spin:   RELAXED agent loads (no buffer_inv per poll!) + s_sleep
// - exit:   single ACQUIRE fence (one buffer_inv/block)
__device__ __forceinline__ void grid_bar(int* bar) {
    __syncthreads();
    if (threadIdx.x == 0) {
        int g = __hip_atomic_load(&bar[1], __ATOMIC_RELAXED, __HIP_MEMORY_SCOPE_AGENT);
        int old = __hip_atomic_fetch_add(&bar[0], 1, __ATOMIC_RELEASE, __HIP_MEMORY_SCOPE_AGENT);
        if (old == NB - 1) {
            __hip_atomic_store(&bar[0], 0, __ATOMIC_RELAXED, __HIP_MEMORY_SCOPE_AGENT);
            __hip_atomic_store(&bar[1], g + 1, __ATOMIC_RELEASE, __HIP_MEMORY_SCOPE_AGENT);
        } else {
            int spins = 0;
            while (__hip_atomic_load(&bar[1], __ATOMIC_RELAXED, __HIP_MEMORY_SCOPE_AGENT) == g) {
                __builtin_amdgcn_s_sleep(8);
                if (++spins > (1 << 17)) break;   // ~30ms failsafe
            }
        }
        __builtin_amdgcn_fence(__ATOMIC_ACQUIRE, "agent");   // one inv at exit
    }
    __syncthreads();
}

__global__ __launch_bounds__(256) void k_init(float* __restrict__ b_ij,
                                              int* __restrict__ bar) {
    int t = blockIdx.x * 256 + threadIdx.x;
    if (t < C_ * J_) b_ij[t] = 0.0f;
    if (t < 16) bar[t] = 0;
}

__global__ __launch_bounds__(NT) void k_persist(
    const float* __restrict__ x, const float* __restrict__ W,
    float* __restrict__ out,
    uint4* __restrict__ Bs4, uint4* __restrict__ Bt4,
    uint4* __restrict__ Wf4, uint4* __restrict__ Af4,
    unsigned short* __restrict__ W2, unsigned short* __restrict__ Vf,
    float* __restrict__ b_ij, int* __restrict__ bar)
{
    const int bid = blockIdx.x;
    const int t   = threadIdx.x;
    const int w   = t >> 6;     // wave 0..7
    const int L   = t & 63;     // lane
    __shared__ float lds[10240];   // 40 KB

    // ================= PACK (2448 tasks) =================
    for (int task = bid; task < 2448; task += NB) {
        __syncthreads();
        if (task < 1152) {                       // --- Bs: x -> sgemm B-frags
            const int nt = task / 36, kbg = task % 36;
            const int b0 = nt * 16, k0 = kbg * 256;
            #pragma unroll
            for (int p = 0; p < 2; p++) {
                int f4 = p * 512 + t;            // 1024 float4 = 16 rows x 64
                int row = f4 >> 6, c4 = (f4 & 63) << 2;
                *(float4*)&lds[row * 260 + c4] =
                    *(const float4*)&x[(size_t)(b0 + row) * K1 + k0 + c4];
            }
            __syncthreads();
            const int q = t >> 6;                // 0..7
            const int row = L & 15;
            const int col = q * 32 + ((L >> 4) << 3);
            const float* s = &lds[row * 260 + col];
            uint4 o;
            o.x = pack2(s[0], s[1]); o.y = pack2(s[2], s[3]);
            o.z = pack2(s[4], s[5]); o.w = pack2(s[6], s[7]);
            Bs4[((size_t)nt * NKB + kbg * 8 + q) * 64 + L] = o;
        } else if (task < 2304) {                // --- Bt: x^T -> tgemm B-frags
            const int b2 = task - 1152;
            const int kb = b2 & 15, ntg = b2 >> 4;
            const int b0 = kb * 32, n0 = ntg * 128;
            #pragma unroll
            for (int p = 0; p < 2; p++) {
                int f4 = p * 512 + t;            // 1024 float4 = 32 rows x 32
                int row = f4 >> 5, c4 = (f4 & 31) << 2;
                *(float4*)&lds[row * 132 + c4] =
                    *(const float4*)&x[(size_t)(b0 + row) * K1 + n0 + c4];
            }
            __syncthreads();
            const int ntl = t >> 6;
            const int bb = (L >> 4) << 3;
            const int nl = ntl * 16 + (L & 15);
            float v[8];
            #pragma unroll
            for (int e = 0; e < 8; e++) v[e] = lds[(bb + e) * 132 + nl];
            uint4 o;
            o.x = pack2(v[0], v[1]); o.y = pack2(v[2], v[3]);
            o.z = pack2(v[4], v[5]); o.w = pack2(v[6], v[7]);
            Bt4[((size_t)(ntg * 8 + ntl) * KBT + kb) * 64 + L] = o;
        } else {                                 // --- W chunk (8 c-rows) -> Wf + W2
            const int c0 = (task - 2304) * 8;
            #pragma unroll
            for (int p = 0; p < 5; p++) {
                int f4 = p * 512 + t;            // 2560 float4 = 8 x 320
                int cc = f4 / 320, off4 = (f4 % 320) << 2;
                *(float4*)&lds[cc * 1280 + off4] =
                    *(const float4*)&W[(size_t)(c0 + cc) * 1280 + off4];
            }
            __syncthreads();
            #pragma unroll
            for (int p = 0; p < 3; p++) {        // Wf: 1280 frags (j,i,m)
                int o = p * 512 + t;
                if (o < 1280) {
                    int j = o >> 7, i = (o >> 4) & 7, m = o & 15;
                    int k0 = i * C_ + c0;
                    int Lw = m | (((k0 >> 3) & 3) << 4);
                    float v[8];
                    #pragma unroll
                    for (int e = 0; e < 8; e++)
                        v[e] = lds[e * 1280 + j * 128 + m * 8 + i];
                    uint4 og;
                    og.x = pack2(v[0], v[1]); og.y = pack2(v[2], v[3]);
                    og.z = pack2(v[4], v[5]); og.w = pack2(v[6], v[7]);
                    Wf4[((size_t)j * NKB + (k0 >> 5)) * 64 + Lw] = og;
                }
            }
            #pragma unroll
            for (int p = 0; p < 2; p++) {        // W2[j][i][c][s] rows
                int o = p * 512 + t;
                if (o < 640) {
                    int j = o >> 6, i = (o >> 3) & 7, cc = o & 7;
                    unsigned int r8[8];
                    #pragma unroll
                    for (int h = 0; h < 8; h++)
                        r8[h] = pack2(lds[cc * 1280 + j * 128 + (2 * h) * 8 + i],
                                      lds[cc * 1280 + j * 128 + (2 * h + 1) * 8 + i]);
                    unsigned short* dst = W2 + ((size_t)(j * 8 + i) * C_ + c0 + cc) * 16;
                    *(uint4*)dst       = make_uint4(r8[0], r8[1], r8[2], r8[3]);
                    *(uint4*)(dst + 8) = make_uint4(r8[4], r8[5], r8[6], r8[7]);
                }
            }
        }
    }
    grid_bar(bar);

    const short8* AfS = (const short8*)Af4;
    const short8* BsS = (const short8*)Bs4;
    const short8* BtS = (const short8*)Bt4;
    const short8* VfS = (const short8*)Vf;

    for (int it = 0; it < 3; it++) {
        // ============ FOLD: Af = softmax(b_ij) * Wf (360 tasks) ============
        for (int task = bid; task < 360; task += NB) {
            __syncthreads();
            const int j   = task / 36;
            const int kb0 = (task % 36) * 8;
            const int k0  = kb0 * 32;            // multiple of 256
            if (t < 256) {
                int c = (k0 + t) % C_;
                float bv[J_], mx = -1e30f;
                #pragma unroll
                for (int jj = 0; jj < J_; jj++) {
                    bv[jj] = b_ij[c * J_ + jj]; mx = fmaxf(mx, bv[jj]);
                }
                float sum = 0.0f;
                #pragma unroll
                for (int jj = 0; jj < J_; jj++) sum += __expf(bv[jj] - mx);
                lds[t] = __expf(bv[j] - mx) / sum;
            }
            __syncthreads();
            const size_t flat = ((size_t)j * NKB + kb0 + w) * 64 + L;
            const int off = w * 32 + ((L >> 4) << 3);
            uint4 wv = Wf4[flat];
            unsigned int u[4] = {wv.x, wv.y, wv.z, wv.w};
            uint4 o; unsigned int* po = (unsigned int*)&o;
            #pragma unroll
            for (int h = 0; h < 4; h++) {
                float f0 = __uint_as_float(u[h] << 16)        * lds[off + 2 * h];
                float f1 = __uint_as_float(u[h] & 0xffff0000u) * lds[off + 2 * h + 1];
                po[h] = pack2(f0, f1);
            }
            Af4[flat] = o;
        }
        grid_bar(bar);

        // ======= SGEMM + REDUCE + SQUASH (80 tasks: 2j x 2nt, K in-block) =======
        for (int task = bid; task < 80; task += NB) {
            __syncthreads();
            const int ntp = task & 15, jp = task >> 4;
            const int j0 = jp * 2, nt0 = ntp * 2;
            const int kb0 = w * 36;
            const short8* pA0 = AfS + ((size_t)j0 * NKB + kb0) * 64 + L;
            const short8* pA1 = pA0 + (size_t)NKB * 64;
            const short8* pB0 = BsS + ((size_t)nt0 * NKB + kb0) * 64 + L;
            const short8* pB1 = pB0 + (size_t)NKB * 64;
            floatx4 c00 = {0.f,0.f,0.f,0.f}, c01 = c00, c10 = c00, c11 = c00;
            #pragma unroll 4
            for (int i = 0; i < 36; i++) {
                short8 a0 = pA0[i * 64], a1 = pA1[i * 64];
                short8 b0 = pB0[i * 64], b1 = pB1[i * 64];
                c00 = __builtin_amdgcn_mfma_f32_16x16x32_bf16(a0, b0, c00, 0, 0, 0);
                c01 = __builtin_amdgcn_mfma_f32_16x16x32_bf16(a0, b1, c01, 0, 0, 0);
                c10 = __builtin_amdgcn_mfma_f32_16x16x32_bf16(a1, b0, c10, 0, 0, 0);
                c11 = __builtin_amdgcn_mfma_f32_16x16x32_bf16(a1, b1, c11, 0, 0, 0);
            }
            const int col = L & 15, rw = (L >> 4) << 2;
            float* base = &lds[w * 1024];
            #pragma unroll
            for (int r = 0; r < 4; r++) {
                base[      (rw + r) * 16 + col] = c00[r];
                base[256 + (rw + r) * 16 + col] = c01[r];
                base[512 + (rw + r) * 16 + col] = c10[r];
                base[768 + (rw + r) * 16 + col] = c11[r];
            }
            __syncthreads();
            if (t < 64) {
                const int jq = t >> 5, nq = (t >> 4) & 1, bl = t & 15;
                const int qoff = (jq * 2 + nq) * 256;
                float sv[16]; float msq = 0.f;
                #pragma unroll
                for (int s = 0; s < 16; s++) {
                    float a = 0.f;
                    #pragma unroll
                    for (int w8 = 0; w8 < 8; w8++)
                        a += lds[w8 * 1024 + qoff + s * 16 + bl];
                    sv[s] = a; msq += a * a;
                }
                const float scale = msq / ((1.f + msq) * sqrtf(msq));
                const int j = j0 + jq;
                const int b = (nt0 + nq) * 16 + bl;
                if (it < 2) {
                    const int kb = b >> 5, lh = (b >> 3) & 3, e = b & 7;
                    #pragma unroll
                    for (int s = 0; s < 16; s++)
                        Vf[((size_t)(j * KBT + kb) * 64 + (s | (lh << 4))) * 8 + e] =
                            f2bf(sv[s] * scale);
                } else {
                    float o16[16];
                    #pragma unroll
                    for (int s = 0; s < 16; s++) o16[s] = sv[s] * scale;
                    float* dst = &out[((size_t)b * J_ + j) * S_];
                    #pragma unroll
                    for (int r4 = 0; r4 < 4; r4++)
                        *(float4*)(dst + r4 * 4) = *(float4*)(o16 + r4 * 4);
                }
            }
        }
        if (it == 2) return;
        grid_bar(bar);

        // ============ TGEMM + fused b_ij update (720 tasks) ============
        for (int task = bid; task < 720; task += NB) {
            __syncthreads();
            const int j = task / 72, ntg = task % 72;
            const int nt = ntg * 8 + w;
            const short8* pA = VfS + (size_t)j * KBT * 64 + L;
            const short8* pB = BtS + (size_t)nt * KBT * 64 + L;
            floatx4 a = {0.f, 0.f, 0.f, 0.f};
            #pragma unroll
            for (int kb = 0; kb < KBT; kb++)
                a = __builtin_amdgcn_mfma_f32_16x16x32_bf16(pA[kb * 64], pB[kb * 64], a, 0, 0, 0);
            const int col = L & 15, rw = (L >> 4) << 2;
            #pragma unroll
            for (int r = 0; r < 4; r++)
                lds[(rw + r) * 132 + w * 16 + col] = a[r];
            __syncthreads();
            if (t < 128) {
                const int n0 = ntg * 128;
                const int i = n0 / C_, c0 = n0 % C_;
                const int c = c0 + t;
                const unsigned short* wp = W2 + ((size_t)(j * 8 + i) * C_ + c) * 16;
                uint4 w0 = *(const uint4*)wp;
                uint4 w1 = *(const uint4*)(wp + 8);
                unsigned int uw[8] = {w0.x, w0.y, w0.z, w0.w, w1.x, w1.y, w1.z, w1.w};
                float sum = 0.f;
                #pragma unroll
                for (int h = 0; h < 8; h++) {
                    sum += lds[(2 * h) * 132 + t]     * __uint_as_float(uw[h] << 16);
                    sum += lds[(2 * h + 1) * 132 + t] * __uint_as_float(uw[h] & 0xffff0000u);
                }
                atomicAdd(&b_ij[c * J_ + j], sum * (1.0f / 512.f));
            }
        }
        grid_bar(bar);
    }
}

// ---------------------------------------------------------------------------
extern "C" void kernel_launch(void* const* d_in, const int* in_sizes, int n_in,
                              void* d_out, int out_size, void* d_ws, size_t ws_size,
                              hipStream_t stream) {
    const float* x = (const float*)d_in[0];   // [512][8][1152]
    const float* W = (const float*)d_in[1];   // [1152][10][16][8]
    float* out = (float*)d_out;               // [512][10][16][1]
    float* ws  = (float*)d_ws;

    // workspace layout (floats, 16B-aligned)
    float* Bs_f = ws;                    // 2,359,296
    float* Bt_f = Bs_f + 2359296;        // 2,359,296
    float* Wf_f = Bt_f + 2359296;        //   737,280
    float* Af_f = Wf_f + 737280;         //   737,280
    float* W2_f = Af_f + 737280;         //   737,280
    float* Vf_f = W2_f + 737280;         //    40,960
    float* bij  = Vf_f + 40960;          //    11,520
    int*   bar  = (int*)(bij + 11520);   //        16
    // total ~6.98M floats = 27.9 MB

    k_init<<<46, 256, 0, stream>>>(bij, bar);
    k_persist<<<NB, NT, 0, stream>>>(x, W, out,
                                     (uint4*)Bs_f, (uint4*)Bt_f,
                                     (uint4*)Wf_f, (uint4*)Af_f,
                                     (unsigned short*)W2_f, (unsigned short*)Vf_f,
                                     bij, bar);
}

// Round 6
// 143.832 us; speedup vs baseline: 4.7855x; 2.4541x over previous
//
#include <hip/hip_runtime.h>
#include <math.h>

#define B_  512
#define I_  8
#define C_  1152
#define J_  10
#define S_  16
#define K1  9216
#define NKB 288     // sgemm K-blocks (K=9216/32)
#define KBT 16      // tgemm K-blocks (K=512/32)

typedef short short8 __attribute__((ext_vector_type(8)));
typedef float floatx4 __attribute__((ext_vector_type(4)));

__device__ inline unsigned short f2bf(float f) {
    unsigned int u = __float_as_uint(f);
    return (unsigned short)((u + 0x7FFFu + ((u >> 16) & 1u)) >> 16);
}
__device__ inline unsigned int pack2(float a, float b) {
    return (unsigned int)f2bf(a) | ((unsigned int)f2bf(b) << 16);
}

// ---------------------------------------------------------------------------
// PACK: 721 blocks x 512 threads.
//  task < 576 : x tile (32 b x 256 k) -> Bs frags AND Bt frags (x read ONCE)
//  task < 720 : W chunk (8 c-rows) -> Wf (A-frag layout) + W2 ([j][i][c][s])
//  task ==720 : zero b_ij
__global__ __launch_bounds__(512) void k_pack(const float* __restrict__ x,
                                              const float* __restrict__ W,
                                              uint4* __restrict__ Bs,
                                              uint4* __restrict__ Bt,
                                              uint4* __restrict__ Wf,
                                              unsigned short* __restrict__ W2,
                                              float* __restrict__ b_ij) {
    __shared__ float lds[10240];   // 40 KB
    const int task = blockIdx.x;
    const int t = threadIdx.x;
    const int w = t >> 6, L = t & 63, quad = L >> 4;

    if (task < 576) {                       // ---- x tile -> Bs + Bt
        const int bt = task / 36, kt = task % 36;
        const int b0 = bt * 32, k0 = kt * 256;
        #pragma unroll
        for (int p = 0; p < 4; p++) {       // 2048 float4 = 32 rows x 64
            int f4 = p * 512 + t;
            int row = f4 >> 6, c4 = (f4 & 63) << 2;
            *(float4*)&lds[row * 260 + c4] =
                *(const float4*)&x[(size_t)(b0 + row) * K1 + k0 + c4];
        }
        __syncthreads();
        // Bs frags: 16 per tile (2 nt x 8 kb); wave w -> kb q=w, p -> nt
        #pragma unroll
        for (int p = 0; p < 2; p++) {
            const int bl = p * 16 + (L & 15);
            const float* s = &lds[bl * 260 + w * 32 + quad * 8];
            uint4 o;
            o.x = pack2(s[0], s[1]); o.y = pack2(s[2], s[3]);
            o.z = pack2(s[4], s[5]); o.w = pack2(s[6], s[7]);
            Bs[((size_t)(bt * 2 + p) * NKB + kt * 8 + w) * 64 + L] = o;
        }
        // Bt frags: 16 per tile (16 n-tiles x 1 kb); wave w -> ntl {2w, 2w+1}
        #pragma unroll
        for (int p = 0; p < 2; p++) {
            const int ntl = w * 2 + p;
            const int nl = ntl * 16 + (L & 15);
            float v[8];
            #pragma unroll
            for (int e = 0; e < 8; e++) v[e] = lds[(quad * 8 + e) * 260 + nl];
            uint4 o;
            o.x = pack2(v[0], v[1]); o.y = pack2(v[2], v[3]);
            o.z = pack2(v[4], v[5]); o.w = pack2(v[6], v[7]);
            Bt[((size_t)(kt * 16 + ntl) * KBT + bt) * 64 + L] = o;
        }
    } else if (task < 720) {                // ---- W chunk -> Wf + W2
        const int c0 = (task - 576) * 8;
        #pragma unroll
        for (int p = 0; p < 5; p++) {       // 2560 float4 = 8 x 320
            int f4 = p * 512 + t;
            int cc = f4 / 320, off4 = (f4 % 320) << 2;
            *(float4*)&lds[cc * 1280 + off4] =
                *(const float4*)&W[(size_t)(c0 + cc) * 1280 + off4];
        }
        __syncthreads();
        #pragma unroll
        for (int p = 0; p < 3; p++) {       // Wf: 1280 frags (j,i,m)
            int o = p * 512 + t;
            if (o < 1280) {
                int j = o >> 7, i = (o >> 4) & 7, m = o & 15;
                int k0w = i * C_ + c0;
                int Lw = m | (((k0w >> 3) & 3) << 4);
                float v[8];
                #pragma unroll
                for (int e = 0; e < 8; e++)
                    v[e] = lds[e * 1280 + j * 128 + m * 8 + i];
                uint4 og;
                og.x = pack2(v[0], v[1]); og.y = pack2(v[2], v[3]);
                og.z = pack2(v[4], v[5]); og.w = pack2(v[6], v[7]);
                Wf[((size_t)j * NKB + (k0w >> 5)) * 64 + Lw] = og;
            }
        }
        #pragma unroll
        for (int p = 0; p < 2; p++) {       // W2[j][i][c][s]
            int o = p * 512 + t;
            if (o < 640) {
                int j = o >> 6, i = (o >> 3) & 7, cc = o & 7;
                unsigned int r8[8];
                #pragma unroll
                for (int h = 0; h < 8; h++)
                    r8[h] = pack2(lds[cc * 1280 + j * 128 + (2 * h) * 8 + i],
                                  lds[cc * 1280 + j * 128 + (2 * h + 1) * 8 + i]);
                unsigned short* dst = W2 + ((size_t)(j * 8 + i) * C_ + c0 + cc) * 16;
                *(uint4*)dst       = make_uint4(r8[0], r8[1], r8[2], r8[3]);
                *(uint4*)(dst + 8) = make_uint4(r8[4], r8[5], r8[6], r8[7]);
            }
        }
    } else {                                // ---- zero b_ij
        for (int idx = t; idx < C_ * J_; idx += 512) b_ij[idx] = 0.0f;
    }
}

// ---------------------------------------------------------------------------
// SGEMM + fused fold + reduce + squash.
// grid 160 = j(10) x ntp(16); block 256 (4 waves, K-split 4x72).
// mode 0: uniform cnorm=0.1 (skip fold, scale at squash), write Vf
// mode 1: softmax fold, write Vf
// mode 2: softmax fold, write out
__global__ __launch_bounds__(256) void k_sgemm_f(const short8* __restrict__ Wf,
                                                 const short8* __restrict__ Bs,
                                                 const float* __restrict__ b_ij,
                                                 unsigned short* __restrict__ Vf,
                                                 float* __restrict__ out,
                                                 int mode) {
    __shared__ float sm[1152 + 2048];   // cn[1152] + acc[4 waves][2 nt][256]
    const int t = threadIdx.x, w = t >> 6, L = t & 63, quad = L >> 4;
    const int j = blockIdx.x >> 4;
    const int ntp = blockIdx.x & 15;

    if (mode) {
        for (int c = t; c < C_; c += 256) {
            float bv[J_], mx = -1e30f;
            #pragma unroll
            for (int jj = 0; jj < J_; jj++) {
                bv[jj] = b_ij[c * J_ + jj]; mx = fmaxf(mx, bv[jj]);
            }
            float sum = 0.0f;
            #pragma unroll
            for (int jj = 0; jj < J_; jj++) sum += __expf(bv[jj] - mx);
            sm[c] = __expf(bv[j] - mx) / sum;
        }
    }
    __syncthreads();

    const short8* pA  = Wf + ((size_t)j * NKB + w * 72) * 64 + L;
    const short8* pB0 = Bs + ((size_t)(ntp * 2) * NKB + w * 72) * 64 + L;
    const short8* pB1 = pB0 + (size_t)NKB * 64;
    floatx4 c0 = {0.f, 0.f, 0.f, 0.f}, c1 = c0;

    if (mode) {
        #pragma unroll 1
        for (int half = 0; half < 2; half++) {
            #pragma unroll 4
            for (int ii = 0; ii < 36; ii++) {
                const int i = half * 36 + ii;
                short8 a = pA[i * 64];
                const int cb = ii * 32 + quad * 8;
                float4 cl = *(const float4*)&sm[cb];
                float4 ch = *(const float4*)&sm[cb + 4];
                float cn8[8] = {cl.x, cl.y, cl.z, cl.w, ch.x, ch.y, ch.z, ch.w};
                unsigned int* au = (unsigned int*)&a;
                short8 a2;
                unsigned int* ao = (unsigned int*)&a2;
                #pragma unroll
                for (int h = 0; h < 4; h++) {
                    float f0 = __uint_as_float(au[h] << 16)         * cn8[2 * h];
                    float f1 = __uint_as_float(au[h] & 0xffff0000u) * cn8[2 * h + 1];
                    ao[h] = pack2(f0, f1);
                }
                c0 = __builtin_amdgcn_mfma_f32_16x16x32_bf16(a2, pB0[i * 64], c0, 0, 0, 0);
                c1 = __builtin_amdgcn_mfma_f32_16x16x32_bf16(a2, pB1[i * 64], c1, 0, 0, 0);
            }
        }
    } else {
        #pragma unroll 4
        for (int i = 0; i < 72; i++) {
            short8 a = pA[i * 64];
            c0 = __builtin_amdgcn_mfma_f32_16x16x32_bf16(a, pB0[i * 64], c0, 0, 0, 0);
            c1 = __builtin_amdgcn_mfma_f32_16x16x32_bf16(a, pB1[i * 64], c1, 0, 0, 0);
        }
    }

    const int col = L & 15, rw = quad << 2;
    float* base = &sm[1152 + w * 512];
    #pragma unroll
    for (int r = 0; r < 4; r++) {
        base[      (rw + r) * 16 + col] = c0[r];
        base[256 + (rw + r) * 16 + col] = c1[r];
    }
    __syncthreads();

    if (t < 32) {
        const int ntl = t >> 4, bl = t & 15;
        float sv[S_]; float msq = 0.f;
        #pragma unroll
        for (int s = 0; s < S_; s++) {
            float a = 0.f;
            #pragma unroll
            for (int w4 = 0; w4 < 4; w4++)
                a += sm[1152 + w4 * 512 + ntl * 256 + s * 16 + bl];
            if (mode == 0) a *= 0.1f;
            sv[s] = a; msq += a * a;
        }
        const float scale = msq / ((1.f + msq) * sqrtf(msq));
        const int b = ntp * 32 + t;          // global b (0..511)
        if (mode < 2) {
            const int kb = b >> 5, lh = (b >> 3) & 3, e = b & 7;
            #pragma unroll
            for (int s = 0; s < S_; s++)
                Vf[((size_t)(j * KBT + kb) * 64 + (s | (lh << 4))) * 8 + e] =
                    f2bf(sv[s] * scale);
        } else {
            float o16[S_];
            #pragma unroll
            for (int s = 0; s < S_; s++) o16[s] = sv[s] * scale;
            float* dst = &out[((size_t)b * J_ + j) * S_];
            #pragma unroll
            for (int r4 = 0; r4 < 4; r4++)
                *(float4*)(dst + r4 * 4) = *(float4*)(o16 + r4 * 4);
        }
    }
}

// ---------------------------------------------------------------------------
// TGEMM + fused b_ij update. grid(72 ntg, 10 j), 512 threads (8 waves).
__global__ __launch_bounds__(512) void k_tgemm_bup(const short8* __restrict__ Vf,
                                                   const short8* __restrict__ Bt,
                                                   const unsigned short* __restrict__ W2,
                                                   float* __restrict__ b_ij) {
    __shared__ float Tl[16 * 132];
    const int t = threadIdx.x, w = t >> 6, L = t & 63;
    const int j = blockIdx.y, ntg = blockIdx.x;
    const int nt = ntg * 8 + w;
    const short8* pA = Vf + (size_t)j * KBT * 64 + L;
    const short8* pB = Bt + (size_t)nt * KBT * 64 + L;
    floatx4 a = {0.f, 0.f, 0.f, 0.f};
    #pragma unroll
    for (int kb = 0; kb < KBT; kb++)
        a = __builtin_amdgcn_mfma_f32_16x16x32_bf16(pA[kb * 64], pB[kb * 64], a, 0, 0, 0);
    const int col = L & 15, rw = (L >> 4) << 2;
    #pragma unroll
    for (int r = 0; r < 4; r++)
        Tl[(rw + r) * 132 + w * 16 + col] = a[r];
    __syncthreads();
    if (t < 128) {
        const int n0 = ntg * 128;
        const int i = n0 / C_, c0 = n0 % C_;
        const int c = c0 + t;
        const unsigned short* wp = W2 + ((size_t)(j * 8 + i) * C_ + c) * 16;
        uint4 w0 = *(const uint4*)wp;
        uint4 w1 = *(const uint4*)(wp + 8);
        unsigned int uw[8] = {w0.x, w0.y, w0.z, w0.w, w1.x, w1.y, w1.z, w1.w};
        float sum = 0.f;
        #pragma unroll
        for (int h = 0; h < 8; h++) {
            sum += Tl[(2 * h) * 132 + t]     * __uint_as_float(uw[h] << 16);
            sum += Tl[(2 * h + 1) * 132 + t] * __uint_as_float(uw[h] & 0xffff0000u);
        }
        atomicAdd(&b_ij[c * J_ + j], sum * (1.0f / 512.f));
    }
}

// ---------------------------------------------------------------------------
extern "C" void kernel_launch(void* const* d_in, const int* in_sizes, int n_in,
                              void* d_out, int out_size, void* d_ws, size_t ws_size,
                              hipStream_t stream) {
    const float* x = (const float*)d_in[0];   // [512][8][1152]
    const float* W = (const float*)d_in[1];   // [1152][10][16][8]
    float* out = (float*)d_out;               // [512][10][16][1]
    float* ws  = (float*)d_ws;

    // workspace layout (floats, 16B-aligned)
    float* Bs_f = ws;                    // 2,359,296
    float* Bt_f = Bs_f + 2359296;        // 2,359,296
    float* Wf_f = Bt_f + 2359296;        //   737,280
    float* W2_f = Wf_f + 737280;         //   737,280
    float* Vf_f = W2_f + 737280;         //    40,960
    float* bij  = Vf_f + 40960;          //    11,520
    // total 6,245,632 floats ~= 25 MB

    k_pack<<<721, 512, 0, stream>>>(x, W, (uint4*)Bs_f, (uint4*)Bt_f,
                                    (uint4*)Wf_f, (unsigned short*)W2_f, bij);

    k_sgemm_f<<<160, 256, 0, stream>>>((const short8*)Wf_f, (const short8*)Bs_f,
                                       bij, (unsigned short*)Vf_f, out, 0);
    k_tgemm_bup<<<dim3(72, 10), 512, 0, stream>>>(
        (const short8*)Vf_f, (const short8*)Bt_f, (const unsigned short*)W2_f, bij);

    k_sgemm_f<<<160, 256, 0, stream>>>((const short8*)Wf_f, (const short8*)Bs_f,
                                       bij, (unsigned short*)Vf_f, out, 1);
    k_tgemm_bup<<<dim3(72, 10), 512, 0, stream>>>(
        (const short8*)Vf_f, (const short8*)Bt_f, (const unsigned short*)W2_f, bij);

    k_sgemm_f<<<160, 256, 0, stream>>>((const short8*)Wf_f, (const short8*)Bs_f,
                                       bij, (unsigned short*)Vf_f, out, 2);
}